// Round 1
// baseline (348.188 us; speedup 1.0000x reference)
//
#include <hip/hip_runtime.h>

// MHA forward, MI355X/gfx950. All matmuls via v_mfma_f32_16x16x32_f16.
// Layouts (verified per cdna_hip_programming.md §3):
//   A-frag:  A[m=lane&15][k=quad*8+j]
//   B-frag:  B[k=quad*8+j][n=lane&15]
//   C/D   :  col=lane&15, row=quad*4+reg
typedef _Float16 half8 __attribute__((ext_vector_type(8)));
typedef float f32x4 __attribute__((ext_vector_type(4)));

#define MFMA16(a, b, c) __builtin_amdgcn_mfma_f32_16x16x32_f16((a), (b), (c), 0, 0, 0)

static constexpr int Bc = 2, Sc = 2048, DIMc = 1024, Hc = 16, HDc = 64;
static constexpr int Mc = Bc * Sc;        // 4096
static constexpr int NQKV = 3 * DIMc;     // 3072

// ---------------- prep kernels (fp32 -> f16, weight repack) ----------------

__global__ void k_cvt_x(const float* __restrict__ x, _Float16* __restrict__ xh) {
  int i = blockIdx.x * 256 + threadIdx.x;
  xh[i] = (_Float16)x[i];
}

// WallT[n][d], n = p*1024 + h*64 + e  (B^T layout for the QKV GEMM)
__global__ void k_prep_wqkv(const float* __restrict__ Wq, const float* __restrict__ Wk,
                            const float* __restrict__ Wv, _Float16* __restrict__ WallT) {
  int i = blockIdx.x * 256 + threadIdx.x;       // over 3072*1024
  int d = i & (DIMc - 1);
  int n = i >> 10;
  int p = n >> 10;
  int rem = n & (DIMc - 1);
  int h = rem >> 6, e = rem & 63;
  const float* W = (p == 0) ? Wq : (p == 1) ? Wk : Wv;
  WallT[i] = (_Float16)W[(h * DIMc + d) * HDc + e];
}

// WoT[n][d] = Wo[d][n]
__global__ void k_prep_wo(const float* __restrict__ Wo, _Float16* __restrict__ WoT) {
  int i = blockIdx.x * 256 + threadIdx.x;       // over 1024*1024
  int d = i & (DIMc - 1);
  int n = i >> 10;
  WoT[i] = (_Float16)Wo[d * DIMc + n];
}

// ---------------- GEMM: x[4096,1024] @ Wall -> q,k,v [B,H,S,64] + bias -----

__global__ __launch_bounds__(256) void k_gemm_qkv(
    const _Float16* __restrict__ A, const _Float16* __restrict__ Bt,
    const float* __restrict__ bq, const float* __restrict__ bk, const float* __restrict__ bv,
    _Float16* __restrict__ qh, _Float16* __restrict__ kh, _Float16* __restrict__ vh) {
  __shared__ _Float16 As[128 * 40];   // [m][k], pad 32->40 halves
  __shared__ _Float16 Bs[128 * 40];   // [n][k]
  const int tid = threadIdx.x;
  const int lane = tid & 63, wave = tid >> 6;
  const int quad = lane >> 4, mr = lane & 15;
  const int wm = wave >> 1, wn = wave & 1;
  const int m0 = blockIdx.y * 128, n0 = blockIdx.x * 128;

  f32x4 acc[4][4];
  for (int i = 0; i < 4; i++)
    for (int j = 0; j < 4; j++) acc[i][j] = f32x4{0.f, 0.f, 0.f, 0.f};

  for (int k0 = 0; k0 < DIMc; k0 += 32) {
    __syncthreads();
    for (int c = tid; c < 512; c += 256) {
      int r = c >> 2, cc = (c & 3) << 3;
      *(half8*)&As[r * 40 + cc] = *(const half8*)&A[(size_t)(m0 + r) * DIMc + k0 + cc];
      *(half8*)&Bs[r * 40 + cc] = *(const half8*)&Bt[(size_t)(n0 + r) * DIMc + k0 + cc];
    }
    __syncthreads();
    half8 af[4], bf[4];
    for (int i = 0; i < 4; i++) af[i] = *(const half8*)&As[(wm * 64 + i * 16 + mr) * 40 + quad * 8];
    for (int i = 0; i < 4; i++) bf[i] = *(const half8*)&Bs[(wn * 64 + i * 16 + mr) * 40 + quad * 8];
    for (int i = 0; i < 4; i++)
      for (int j = 0; j < 4; j++) acc[i][j] = MFMA16(af[i], bf[j], acc[i][j]);
  }

  for (int i = 0; i < 4; i++) {
    for (int j = 0; j < 4; j++) {
      int col = n0 + wn * 64 + j * 16 + mr;          // 0..3071
      int p = col >> 10, rem = col & 1023;
      const float* bias = (p == 0) ? bq : (p == 1) ? bk : bv;
      _Float16* dst = (p == 0) ? qh : (p == 1) ? kh : vh;
      float bb = bias[rem];
      int h = rem >> 6, e = rem & 63;
      for (int r = 0; r < 4; r++) {
        int row = m0 + wm * 64 + i * 16 + quad * 4 + r;   // 0..4095
        int b = row >> 11, s = row & 2047;
        dst[(((size_t)(b * Hc + h)) * Sc + s) * HDc + e] = (_Float16)(acc[i][j][r] + bb);
      }
    }
  }
}

// ---------------- flash attention (causal) ---------------------------------
// grid: x = S/64 q-tiles, y = B*H. 4 waves; wave w owns q rows [qt*64+w*16, +16)

__global__ __launch_bounds__(256) void k_attn(
    const _Float16* __restrict__ qg, const _Float16* __restrict__ kg,
    const _Float16* __restrict__ vg, _Float16* __restrict__ att) {
  const int qt = blockIdx.x;
  const int bh = blockIdx.y;
  const int b = bh >> 4, h = bh & 15;
  const int tid = threadIdx.x, wave = tid >> 6, lane = tid & 63;
  const int quad = lane >> 4, mr = lane & 15;
  const size_t base = (size_t)bh * Sc * HDc;

  __shared__ _Float16 Ks[64 * 72];      // [kv][e], pad 64->72
  __shared__ _Float16 Vt[64 * 72];      // [e][kv] (transposed)
  __shared__ _Float16 Ps[4][16 * 72];   // per-wave P buffer [m][kv]

  const int qrow = qt * 64 + wave * 16 + mr;
  half8 aq0 = *(const half8*)&qg[base + (size_t)qrow * HDc + quad * 8];
  half8 aq1 = *(const half8*)&qg[base + (size_t)qrow * HDc + 32 + quad * 8];

  f32x4 o[4];
  for (int i = 0; i < 4; i++) o[i] = f32x4{0.f, 0.f, 0.f, 0.f};
  float m_i[4], l_i[4];
  for (int r = 0; r < 4; r++) { m_i[r] = -3e30f; l_i[r] = 0.f; }

  for (int t = 0; t <= qt; ++t) {
    __syncthreads();
    for (int c = tid; c < 512; c += 256) {
      int r = c >> 3, cc = (c & 7) << 3;
      *(half8*)&Ks[r * 72 + cc] = *(const half8*)&kg[base + (size_t)(t * 64 + r) * HDc + cc];
      half8 vv = *(const half8*)&vg[base + (size_t)(t * 64 + r) * HDc + cc];
      for (int j = 0; j < 8; ++j) Vt[(cc + j) * 72 + r] = vv[j];
    }
    __syncthreads();

    // S = Q K^T (per wave: 16 q-rows x 64 kv)
    f32x4 sf[4];
    for (int nf = 0; nf < 4; ++nf) {
      half8 b0 = *(const half8*)&Ks[(nf * 16 + mr) * 72 + quad * 8];
      half8 b1 = *(const half8*)&Ks[(nf * 16 + mr) * 72 + 32 + quad * 8];
      f32x4 c = {0.f, 0.f, 0.f, 0.f};
      c = MFMA16(aq0, b0, c);
      c = MFMA16(aq1, b1, c);
      sf[nf] = c;
    }

    const bool diag = (t == qt);
    float rmax[4] = {-3e30f, -3e30f, -3e30f, -3e30f};
    for (int nf = 0; nf < 4; ++nf) {
      int kv = t * 64 + nf * 16 + mr;
      for (int r = 0; r < 4; ++r) {
        float s = sf[nf][r] * 0.125f;   // 1/sqrt(64)
        if (diag && kv > qt * 64 + wave * 16 + quad * 4 + r) s = -3e30f;
        sf[nf][r] = s;
        rmax[r] = fmaxf(rmax[r], s);
      }
    }
    for (int off = 1; off < 16; off <<= 1)
      for (int r = 0; r < 4; ++r) rmax[r] = fmaxf(rmax[r], __shfl_xor(rmax[r], off, 64));

    float alpha[4], rsum[4];
    for (int r = 0; r < 4; ++r) {
      float mn = fmaxf(m_i[r], rmax[r]);
      alpha[r] = __expf(m_i[r] - mn);
      m_i[r] = mn;
      rsum[r] = 0.f;
    }
    for (int nf = 0; nf < 4; ++nf)
      for (int r = 0; r < 4; ++r) {
        float p = __expf(sf[nf][r] - m_i[r]);
        sf[nf][r] = p;
        rsum[r] += p;
      }
    for (int off = 1; off < 16; off <<= 1)
      for (int r = 0; r < 4; ++r) rsum[r] += __shfl_xor(rsum[r], off, 64);
    for (int r = 0; r < 4; ++r) l_i[r] = l_i[r] * alpha[r] + rsum[r];

    // P: C-layout -> LDS -> A-layout (wave-local; DS ops in-order within wave)
    for (int nf = 0; nf < 4; ++nf)
      for (int r = 0; r < 4; ++r)
        Ps[wave][(quad * 4 + r) * 72 + nf * 16 + mr] = (_Float16)sf[nf][r];

    for (int i = 0; i < 4; ++i)
      for (int r = 0; r < 4; ++r) o[i][r] *= alpha[r];

    half8 p0 = *(const half8*)&Ps[wave][mr * 72 + quad * 8];
    half8 p1 = *(const half8*)&Ps[wave][mr * 72 + 32 + quad * 8];
    for (int nf = 0; nf < 4; ++nf) {
      half8 v0 = *(const half8*)&Vt[(nf * 16 + mr) * 72 + quad * 8];
      half8 v1 = *(const half8*)&Vt[(nf * 16 + mr) * 72 + 32 + quad * 8];
      o[nf] = MFMA16(p0, v0, o[nf]);
      o[nf] = MFMA16(p1, v1, o[nf]);
    }
  }

  // att[b][s][h*64+e], concat-head layout for the output GEMM
  for (int nf = 0; nf < 4; ++nf)
    for (int r = 0; r < 4; ++r) {
      int s = qt * 64 + wave * 16 + quad * 4 + r;
      float val = o[nf][r] / l_i[r];
      att[((size_t)(b * Sc + s)) * DIMc + h * HDc + nf * 16 + mr] = (_Float16)val;
    }
}

// ---------------- GEMM: att[4096,1024] @ Wo + bo -> out (fp32) -------------

__global__ __launch_bounds__(256) void k_gemm_out(
    const _Float16* __restrict__ A, const _Float16* __restrict__ Bt,
    const float* __restrict__ bo, float* __restrict__ out) {
  __shared__ _Float16 As[128 * 40];
  __shared__ _Float16 Bs[128 * 40];
  const int tid = threadIdx.x;
  const int lane = tid & 63, wave = tid >> 6;
  const int quad = lane >> 4, mr = lane & 15;
  const int wm = wave >> 1, wn = wave & 1;
  const int m0 = blockIdx.y * 128, n0 = blockIdx.x * 128;

  f32x4 acc[4][4];
  for (int i = 0; i < 4; i++)
    for (int j = 0; j < 4; j++) acc[i][j] = f32x4{0.f, 0.f, 0.f, 0.f};

  for (int k0 = 0; k0 < DIMc; k0 += 32) {
    __syncthreads();
    for (int c = tid; c < 512; c += 256) {
      int r = c >> 2, cc = (c & 3) << 3;
      *(half8*)&As[r * 40 + cc] = *(const half8*)&A[(size_t)(m0 + r) * DIMc + k0 + cc];
      *(half8*)&Bs[r * 40 + cc] = *(const half8*)&Bt[(size_t)(n0 + r) * DIMc + k0 + cc];
    }
    __syncthreads();
    half8 af[4], bf[4];
    for (int i = 0; i < 4; i++) af[i] = *(const half8*)&As[(wm * 64 + i * 16 + mr) * 40 + quad * 8];
    for (int i = 0; i < 4; i++) bf[i] = *(const half8*)&Bs[(wn * 64 + i * 16 + mr) * 40 + quad * 8];
    for (int i = 0; i < 4; i++)
      for (int j = 0; j < 4; j++) acc[i][j] = MFMA16(af[i], bf[j], acc[i][j]);
  }

  for (int i = 0; i < 4; i++) {
    for (int j = 0; j < 4; j++) {
      int col = n0 + wn * 64 + j * 16 + mr;
      float bb = bo[col];
      for (int r = 0; r < 4; r++) {
        int row = m0 + wm * 64 + i * 16 + quad * 4 + r;
        out[(size_t)row * DIMc + col] = acc[i][j][r] + bb;
      }
    }
  }
}

// ---------------- launch ----------------------------------------------------

extern "C" void kernel_launch(void* const* d_in, const int* in_sizes, int n_in,
                              void* d_out, int out_size, void* d_ws, size_t ws_size,
                              hipStream_t stream) {
  const float* x  = (const float*)d_in[0];
  const float* Wq = (const float*)d_in[1];
  const float* bq = (const float*)d_in[2];
  const float* Wk = (const float*)d_in[3];
  const float* bk = (const float*)d_in[4];
  const float* Wv = (const float*)d_in[5];
  const float* bv = (const float*)d_in[6];
  const float* Wo = (const float*)d_in[7];
  const float* bo = (const float*)d_in[8];
  float* out = (float*)d_out;

  // workspace carve-up (f16 elements): total 24M halves = 48 MB
  _Float16* xh    = (_Float16*)d_ws;
  _Float16* WallT = xh + (size_t)Mc * DIMc;          // 4M
  _Float16* WoT   = WallT + (size_t)NQKV * DIMc;     // +3M
  _Float16* qh    = WoT + (size_t)DIMc * DIMc;       // +1M
  _Float16* kh    = qh + (size_t)Bc * Hc * Sc * HDc; // +4M
  _Float16* vh    = kh + (size_t)Bc * Hc * Sc * HDc; // +4M
  _Float16* atth  = vh + (size_t)Bc * Hc * Sc * HDc; // +4M, +4M more used

  k_cvt_x<<<(Mc * DIMc) / 256, 256, 0, stream>>>(x, xh);
  k_prep_wqkv<<<(NQKV * DIMc) / 256, 256, 0, stream>>>(Wq, Wk, Wv, WallT);
  k_prep_wo<<<(DIMc * DIMc) / 256, 256, 0, stream>>>(Wo, WoT);

  k_gemm_qkv<<<dim3(NQKV / 128, Mc / 128), 256, 0, stream>>>(
      xh, WallT, bq, bk, bv, qh, kh, vh);

  k_attn<<<dim3(Sc / 64, Bc * Hc), 256, 0, stream>>>(qh, kh, vh, atth);

  k_gemm_out<<<dim3(DIMc / 128, Mc / 128), 256, 0, stream>>>(atth, WoT, bo, out);
}

// Round 2
// 331.132 us; speedup vs baseline: 1.0515x; 1.0515x over previous
//
#include <hip/hip_runtime.h>

// MHA forward, MI355X/gfx950. All matmuls via v_mfma_f32_16x16x32_f16.
// Fragment layouts (HW-verified per cdna_hip_programming.md §3):
//   A-frag:  A[m=lane&15][k=quad*8+j]
//   B-frag:  B[k=quad*8+j][n=lane&15]
//   C/D   :  col(n)=lane&15, row(m)=quad*4+reg
typedef _Float16 half8 __attribute__((ext_vector_type(8)));
typedef float f32x4 __attribute__((ext_vector_type(4)));

#define MFMA16(a, b, c) __builtin_amdgcn_mfma_f32_16x16x32_f16((a), (b), (c), 0, 0, 0)

static constexpr int Bc = 2, Sc = 2048, DIMc = 1024, Hc = 16, HDc = 64;
static constexpr int Mc = Bc * Sc;        // 4096
static constexpr int NQKV = 3 * DIMc;     // 3072

// ---------------- prep kernels -------------------------------------------

__global__ void k_cvt_x(const float* __restrict__ x, _Float16* __restrict__ xh) {
  int i = blockIdx.x * 256 + threadIdx.x;
  xh[i] = (_Float16)x[i];
}

// W{q,k,v}[h][d][e] (fp32) -> WallT[p*1024 + h*64 + e][d] (f16), LDS tile transpose.
// grid: (16 d-tiles, 48 p*h)
__global__ __launch_bounds__(256) void k_prep_w(
    const float* __restrict__ Wq, const float* __restrict__ Wk,
    const float* __restrict__ Wv, _Float16* __restrict__ WallT) {
  __shared__ float Ls[64 * 65];
  const int dt = blockIdx.x, ph = blockIdx.y;
  const int p = ph >> 4, h = ph & 15;
  const float* W = (p == 0) ? Wq : (p == 1) ? Wk : Wv;
  const int tid = threadIdx.x;
  for (int c = tid; c < 4096; c += 256) {
    int dr = c >> 6, e = c & 63;                        // e fast -> coalesced read
    Ls[e * 65 + dr] = W[h * 65536 + (dt * 64 + dr) * 64 + e];
  }
  __syncthreads();
  for (int c = tid; c < 4096; c += 256) {
    int e = c >> 6, dr = c & 63;                        // dr fast -> coalesced write
    WallT[(size_t)(p * 1024 + h * 64 + e) * 1024 + dt * 64 + dr] = (_Float16)Ls[e * 65 + dr];
  }
}

// Wo[d][n] (fp32) -> WoT[n][d] (f16). grid: (16 d-tiles, 16 n-tiles)
__global__ __launch_bounds__(256) void k_prep_wo(
    const float* __restrict__ Wo, _Float16* __restrict__ WoT) {
  __shared__ float Ls[64 * 65];
  const int dt = blockIdx.x, nt = blockIdx.y;
  const int tid = threadIdx.x;
  for (int c = tid; c < 4096; c += 256) {
    int dr = c >> 6, nl = c & 63;
    Ls[nl * 65 + dr] = Wo[(dt * 64 + dr) * 1024 + nt * 64 + nl];
  }
  __syncthreads();
  for (int c = tid; c < 4096; c += 256) {
    int nl = c >> 6, dr = c & 63;
    WoT[(size_t)(nt * 64 + nl) * 1024 + dt * 64 + dr] = (_Float16)Ls[nl * 65 + dr];
  }
}

// ---------------- GEMM: x @ [Wq|Wk] -> q,k [B,H,S,64] + bias --------------
// grid (16 n-tiles(2048), 32 m-tiles)

__global__ __launch_bounds__(256) void k_gemm_qk(
    const _Float16* __restrict__ A, const _Float16* __restrict__ Bt,
    const float* __restrict__ bq, const float* __restrict__ bk,
    _Float16* __restrict__ qh, _Float16* __restrict__ kh) {
  __shared__ _Float16 As[128 * 40];
  __shared__ _Float16 Bs[128 * 40];
  const int tid = threadIdx.x;
  const int lane = tid & 63, wave = tid >> 6;
  const int quad = lane >> 4, mr = lane & 15;
  const int wm = wave >> 1, wn = wave & 1;
  const int m0 = blockIdx.y * 128, n0 = blockIdx.x * 128;

  f32x4 acc[4][4];
  for (int i = 0; i < 4; i++)
    for (int j = 0; j < 4; j++) acc[i][j] = f32x4{0.f, 0.f, 0.f, 0.f};

  for (int k0 = 0; k0 < DIMc; k0 += 32) {
    __syncthreads();
    for (int c = tid; c < 512; c += 256) {
      int r = c >> 2, cc = (c & 3) << 3;
      *(half8*)&As[r * 40 + cc] = *(const half8*)&A[(size_t)(m0 + r) * DIMc + k0 + cc];
      *(half8*)&Bs[r * 40 + cc] = *(const half8*)&Bt[(size_t)(n0 + r) * DIMc + k0 + cc];
    }
    __syncthreads();
    half8 af[4], bf[4];
    for (int i = 0; i < 4; i++) af[i] = *(const half8*)&As[(wm * 64 + i * 16 + mr) * 40 + quad * 8];
    for (int i = 0; i < 4; i++) bf[i] = *(const half8*)&Bs[(wn * 64 + i * 16 + mr) * 40 + quad * 8];
    for (int i = 0; i < 4; i++)
      for (int j = 0; j < 4; j++) acc[i][j] = MFMA16(af[i], bf[j], acc[i][j]);
  }

  for (int i = 0; i < 4; i++) {
    for (int j = 0; j < 4; j++) {
      int col = n0 + wn * 64 + j * 16 + mr;          // 0..2047
      int p = col >> 10, rem = col & 1023;
      const float* bias = p ? bk : bq;
      _Float16* dst = p ? kh : qh;
      float bb = bias[rem];
      int h = rem >> 6, e = rem & 63;
      for (int r = 0; r < 4; r++) {
        int row = m0 + wm * 64 + i * 16 + quad * 4 + r;
        int b = row >> 11, s = row & 2047;
        dst[(((size_t)(b * Hc + h)) * Sc + s) * HDc + e] = (_Float16)(acc[i][j][r] + bb);
      }
    }
  }
}

// ---------------- GEMM: V^T directly: vT[b*1024+hd][s] = Wv'[hd][:]·x[s][:] + bv
// A = WallT+2048*1024 (rows m = h*64+e over d), Bt = xh (rows n = s over d).
// grid (32 n-tiles(4096), 8 m-tiles(1024))

__global__ __launch_bounds__(256) void k_gemm_vT(
    const _Float16* __restrict__ A, const _Float16* __restrict__ Bt,
    const float* __restrict__ bv, _Float16* __restrict__ vT) {
  __shared__ _Float16 As[128 * 40];
  __shared__ _Float16 Bs[128 * 40];
  const int tid = threadIdx.x;
  const int lane = tid & 63, wave = tid >> 6;
  const int quad = lane >> 4, mr = lane & 15;
  const int wm = wave >> 1, wn = wave & 1;
  const int m0 = blockIdx.y * 128, n0 = blockIdx.x * 128;

  f32x4 acc[4][4];
  for (int i = 0; i < 4; i++)
    for (int j = 0; j < 4; j++) acc[i][j] = f32x4{0.f, 0.f, 0.f, 0.f};

  for (int k0 = 0; k0 < DIMc; k0 += 32) {
    __syncthreads();
    for (int c = tid; c < 512; c += 256) {
      int r = c >> 2, cc = (c & 3) << 3;
      *(half8*)&As[r * 40 + cc] = *(const half8*)&A[(size_t)(m0 + r) * DIMc + k0 + cc];
      *(half8*)&Bs[r * 40 + cc] = *(const half8*)&Bt[(size_t)(n0 + r) * DIMc + k0 + cc];
    }
    __syncthreads();
    half8 af[4], bf[4];
    for (int i = 0; i < 4; i++) af[i] = *(const half8*)&As[(wm * 64 + i * 16 + mr) * 40 + quad * 8];
    for (int i = 0; i < 4; i++) bf[i] = *(const half8*)&Bs[(wn * 64 + i * 16 + mr) * 40 + quad * 8];
    for (int i = 0; i < 4; i++)
      for (int j = 0; j < 4; j++) acc[i][j] = MFMA16(af[i], bf[j], acc[i][j]);
  }

  for (int i = 0; i < 4; i++) {
    int rowb = m0 + wm * 64 + i * 16 + quad * 4;       // e-glob base
    for (int j = 0; j < 4; j++) {
      int col = n0 + wn * 64 + j * 16 + mr;            // s-glob 0..4095
      int b = col >> 11, s = col & 2047;
      for (int r = 0; r < 4; r++) {
        int row = rowb + r;
        vT[(size_t)(b * 1024 + row) * Sc + s] = (_Float16)(acc[i][j][r] + bv[row]);
      }
    }
  }
}

// ---------------- flash attention (causal) --------------------------------
// Q-tile 128 rows/block, 4 waves x 32 rows (2 m-frags). KV-tile 64, dbuf LDS.
// grid: x=16 (qt, paired long+short), y=32 (b*h)

__global__ __launch_bounds__(256) void k_attn(
    const _Float16* __restrict__ qg, const _Float16* __restrict__ kg,
    const _Float16* __restrict__ vTg, _Float16* __restrict__ att) {
  const int xb = blockIdx.x;
  const int qt = (xb & 1) ? (xb >> 1) : (15 - (xb >> 1));   // pair long with short
  const int bh = blockIdx.y;
  const int b = bh >> 4, h = bh & 15;
  const int tid = threadIdx.x, wave = tid >> 6, lane = tid & 63;
  const int quad = lane >> 4, mr = lane & 15;
  const size_t base = (size_t)bh * (Sc * HDc);

  __shared__ _Float16 Ks[2][64 * 72];   // [kv][e], pad 72 (2-way reads: free)
  __shared__ _Float16 Vt[2][64 * 72];   // [e][kv] staged directly from vT global
  __shared__ _Float16 Ps[4][32 * 80];   // per-wave P, stride 80 (bank-shift 8/quad)
  _Float16* Psw = &Ps[wave][0];

  const int qbase = qt * 128 + wave * 32;
  const int qmax = qbase + 31;

  half8 aq[2][2];
  for (int i = 0; i < 2; ++i)
    for (int c = 0; c < 2; ++c)
      aq[i][c] = *(const half8*)&qg[base + (size_t)(qbase + i * 16 + mr) * 64 + c * 32 + quad * 8];

  f32x4 o[2][4];
  float m_i[2][4], l_i[2][4];
  for (int i = 0; i < 2; ++i)
    for (int r = 0; r < 4; ++r) {
      o[i][0] = o[i][1] = o[i][2] = o[i][3] = f32x4{0.f, 0.f, 0.f, 0.f};
      m_i[i][r] = -3e30f; l_i[i][r] = 0.f;
    }

  const int nt = 2 * qt + 2;

  // stage tile 0 -> buf 0 (coalesced half8 both sides)
  for (int c = tid; c < 512; c += 256) {
    int r = c >> 3, cc = (c & 7) << 3;
    *(half8*)&Ks[0][r * 72 + cc] = *(const half8*)&kg[base + (size_t)r * 64 + cc];
    *(half8*)&Vt[0][r * 72 + cc] = *(const half8*)&vTg[base + (size_t)r * Sc + cc];
  }
  __syncthreads();

  for (int t = 0; t < nt; ++t) {
    const int cur = t & 1;
    if (t + 1 < nt) {                       // prefetch next tile into other buf
      const int nxt = cur ^ 1;
      const int kv0 = (t + 1) * 64;
      for (int c = tid; c < 512; c += 256) {
        int r = c >> 3, cc = (c & 7) << 3;
        *(half8*)&Ks[nxt][r * 72 + cc] = *(const half8*)&kg[base + (size_t)(kv0 + r) * 64 + cc];
        *(half8*)&Vt[nxt][r * 72 + cc] = *(const half8*)&vTg[base + (size_t)r * Sc + kv0 + cc];
      }
    }

    if (t * 64 <= qmax) {                   // wave-level skip of fully-masked tiles
      half8 kf0[4], kf1[4], vf0[4], vf1[4];
      for (int nf = 0; nf < 4; ++nf) {
        kf0[nf] = *(const half8*)&Ks[cur][(nf * 16 + mr) * 72 + quad * 8];
        kf1[nf] = *(const half8*)&Ks[cur][(nf * 16 + mr) * 72 + 32 + quad * 8];
        vf0[nf] = *(const half8*)&Vt[cur][(nf * 16 + mr) * 72 + quad * 8];
        vf1[nf] = *(const half8*)&Vt[cur][(nf * 16 + mr) * 72 + 32 + quad * 8];
      }

      f32x4 sf[2][4];
      for (int i = 0; i < 2; ++i)
        for (int nf = 0; nf < 4; ++nf) {
          f32x4 z = {0.f, 0.f, 0.f, 0.f};
          z = MFMA16(aq[i][0], kf0[nf], z);
          z = MFMA16(aq[i][1], kf1[nf], z);
          sf[i][nf] = z;
        }

      const bool needmask = (t * 64 + 63) > qbase;
      float rm[2][4];
      for (int i = 0; i < 2; ++i)
        for (int r = 0; r < 4; ++r) rm[i][r] = -3e30f;
      for (int i = 0; i < 2; ++i)
        for (int nf = 0; nf < 4; ++nf) {
          int kv = t * 64 + nf * 16 + mr;
          for (int r = 0; r < 4; ++r) {
            float s = sf[i][nf][r] * 0.125f;             // 1/sqrt(64)
            if (needmask && kv > qbase + i * 16 + quad * 4 + r) s = -3e30f;
            sf[i][nf][r] = s;
            rm[i][r] = fmaxf(rm[i][r], s);
          }
        }
      for (int off = 1; off < 16; off <<= 1)
        for (int i = 0; i < 2; ++i)
          for (int r = 0; r < 4; ++r) rm[i][r] = fmaxf(rm[i][r], __shfl_xor(rm[i][r], off, 64));

      float alpha[2][4], rs[2][4];
      for (int i = 0; i < 2; ++i)
        for (int r = 0; r < 4; ++r) {
          float mn = fmaxf(m_i[i][r], rm[i][r]);
          alpha[i][r] = __expf(m_i[i][r] - mn);
          m_i[i][r] = mn;
          rs[i][r] = 0.f;
        }
      for (int i = 0; i < 2; ++i)
        for (int nf = 0; nf < 4; ++nf)
          for (int r = 0; r < 4; ++r) {
            float p = __expf(sf[i][nf][r] - m_i[i][r]);
            sf[i][nf][r] = p;
            rs[i][r] += p;
          }
      for (int off = 1; off < 16; off <<= 1)
        for (int i = 0; i < 2; ++i)
          for (int r = 0; r < 4; ++r) rs[i][r] += __shfl_xor(rs[i][r], off, 64);
      for (int i = 0; i < 2; ++i)
        for (int r = 0; r < 4; ++r) l_i[i][r] = l_i[i][r] * alpha[i][r] + rs[i][r];

      // P: C-layout -> per-wave LDS -> A-layout (wave-local, in-order DS)
      for (int i = 0; i < 2; ++i)
        for (int nf = 0; nf < 4; ++nf)
          for (int r = 0; r < 4; ++r)
            Psw[(i * 16 + quad * 4 + r) * 80 + nf * 16 + mr] = (_Float16)sf[i][nf][r];

      for (int i = 0; i < 2; ++i)
        for (int nf = 0; nf < 4; ++nf)
          for (int r = 0; r < 4; ++r) o[i][nf][r] *= alpha[i][r];

      half8 pa[2][2];
      for (int i = 0; i < 2; ++i)
        for (int c = 0; c < 2; ++c)
          pa[i][c] = *(const half8*)&Psw[(i * 16 + mr) * 80 + c * 32 + quad * 8];

      for (int i = 0; i < 2; ++i)
        for (int nf = 0; nf < 4; ++nf) {
          o[i][nf] = MFMA16(pa[i][0], vf0[nf], o[i][nf]);
          o[i][nf] = MFMA16(pa[i][1], vf1[nf], o[i][nf]);
        }
    }
    __syncthreads();
  }

  // att[b][s][h*64+e] concat-head layout
  for (int i = 0; i < 2; ++i)
    for (int r = 0; r < 4; ++r) {
      int s = qbase + i * 16 + quad * 4 + r;
      float inv = 1.0f / l_i[i][r];
      for (int nf = 0; nf < 4; ++nf)
        att[((size_t)(b * Sc + s)) * DIMc + h * HDc + nf * 16 + mr] =
            (_Float16)(o[i][nf][r] * inv);
    }
}

// ---------------- GEMM: att @ Wo + bo -> out (fp32) -----------------------

__global__ __launch_bounds__(256) void k_gemm_out(
    const _Float16* __restrict__ A, const _Float16* __restrict__ Bt,
    const float* __restrict__ bo, float* __restrict__ out) {
  __shared__ _Float16 As[128 * 40];
  __shared__ _Float16 Bs[128 * 40];
  const int tid = threadIdx.x;
  const int lane = tid & 63, wave = tid >> 6;
  const int quad = lane >> 4, mr = lane & 15;
  const int wm = wave >> 1, wn = wave & 1;
  const int m0 = blockIdx.y * 128, n0 = blockIdx.x * 128;

  f32x4 acc[4][4];
  for (int i = 0; i < 4; i++)
    for (int j = 0; j < 4; j++) acc[i][j] = f32x4{0.f, 0.f, 0.f, 0.f};

  for (int k0 = 0; k0 < DIMc; k0 += 32) {
    __syncthreads();
    for (int c = tid; c < 512; c += 256) {
      int r = c >> 2, cc = (c & 3) << 3;
      *(half8*)&As[r * 40 + cc] = *(const half8*)&A[(size_t)(m0 + r) * DIMc + k0 + cc];
      *(half8*)&Bs[r * 40 + cc] = *(const half8*)&Bt[(size_t)(n0 + r) * DIMc + k0 + cc];
    }
    __syncthreads();
    half8 af[4], bf[4];
    for (int i = 0; i < 4; i++) af[i] = *(const half8*)&As[(wm * 64 + i * 16 + mr) * 40 + quad * 8];
    for (int i = 0; i < 4; i++) bf[i] = *(const half8*)&Bs[(wn * 64 + i * 16 + mr) * 40 + quad * 8];
    for (int i = 0; i < 4; i++)
      for (int j = 0; j < 4; j++) acc[i][j] = MFMA16(af[i], bf[j], acc[i][j]);
  }

  for (int i = 0; i < 4; i++) {
    for (int j = 0; j < 4; j++) {
      int col = n0 + wn * 64 + j * 16 + mr;
      float bb = bo[col];
      for (int r = 0; r < 4; r++) {
        int row = m0 + wm * 64 + i * 16 + quad * 4 + r;
        out[(size_t)row * DIMc + col] = acc[i][j][r] + bb;
      }
    }
  }
}

// ---------------- launch ---------------------------------------------------

extern "C" void kernel_launch(void* const* d_in, const int* in_sizes, int n_in,
                              void* d_out, int out_size, void* d_ws, size_t ws_size,
                              hipStream_t stream) {
  const float* x  = (const float*)d_in[0];
  const float* Wq = (const float*)d_in[1];
  const float* bq = (const float*)d_in[2];
  const float* Wk = (const float*)d_in[3];
  const float* bk = (const float*)d_in[4];
  const float* Wv = (const float*)d_in[5];
  const float* bv = (const float*)d_in[6];
  const float* Wo = (const float*)d_in[7];
  const float* bo = (const float*)d_in[8];
  float* out = (float*)d_out;

  _Float16* xh    = (_Float16*)d_ws;                 // 4M halves
  _Float16* WallT = xh + (size_t)Mc * DIMc;          // +4M
  _Float16* WoT   = WallT + (size_t)NQKV * DIMc;     // +3M
  _Float16* qh    = WoT + (size_t)DIMc * DIMc;       // +1M
  _Float16* kh    = qh + (size_t)Mc * DIMc / 4;      // wrong scale? see below
  _Float16* vT    = kh + (size_t)Bc * Hc * Sc * HDc;
  _Float16* atth  = vT + (size_t)Bc * Hc * Sc * HDc;

  // (qh/kh/vT/atth are each B*H*S*HD = 4M halves; Mc*DIMc/4 == 1M is wrong)
  // recompute cleanly:
  {
    _Float16* p = (_Float16*)d_ws;
    xh    = p; p += (size_t)Mc * DIMc;               // 4M
    WallT = p; p += (size_t)NQKV * DIMc;             // 3M
    WoT   = p; p += (size_t)DIMc * DIMc;             // 1M
    qh    = p; p += (size_t)Bc * Hc * Sc * HDc;      // 4M
    kh    = p; p += (size_t)Bc * Hc * Sc * HDc;      // 4M
    vT    = p; p += (size_t)Bc * Hc * Sc * HDc;      // 4M
    atth  = p;                                       // 4M  => 24M halves = 48 MB
  }

  k_cvt_x<<<(Mc * DIMc) / 256, 256, 0, stream>>>(x, xh);
  k_prep_w<<<dim3(16, 48), 256, 0, stream>>>(Wq, Wk, Wv, WallT);
  k_prep_wo<<<dim3(16, 16), 256, 0, stream>>>(Wo, WoT);

  k_gemm_qk<<<dim3(16, Mc / 128), 256, 0, stream>>>(xh, WallT, bq, bk, qh, kh);
  k_gemm_vT<<<dim3(Mc / 128, 8), 256, 0, stream>>>(
      WallT + (size_t)2048 * DIMc, xh, bv, vT);

  k_attn<<<dim3(16, Bc * Hc), 256, 0, stream>>>(qh, kh, vT, atth);

  k_gemm_out<<<dim3(DIMc / 128, Mc / 128), 256, 0, stream>>>(atth, WoT, bo, out);
}

// Round 3
// 240.938 us; speedup vs baseline: 1.4451x; 1.3743x over previous
//
#include <hip/hip_runtime.h>

// MHA forward, MI355X/gfx950.
// Fragment layouts (HW-verified per cdna_hip_programming.md §3):
//   K=32 A-frag: A[m=lane&15][k=quad*8+j]   (half8)
//   K=32 B-frag: B[k=quad*8+j][n=lane&15]   (half8)
//   K=16 A-frag: A[m=lane&15][k=quad*4+j]   (half4)
//   K=16 B-frag: B[k=quad*4+j][n=lane&15]   (half4)
//   C/D (all 16x16): col(n)=lane&15, row(m)=quad*4+reg
// Key chain: S^T from K.Q^T exits in C/D layout == K=16 B-frag layout, so
// P^T feeds O^T = V^T . P^T straight from registers (no LDS round-trip).
typedef _Float16 half8 __attribute__((ext_vector_type(8)));
typedef _Float16 half4 __attribute__((ext_vector_type(4)));
typedef float f32x4 __attribute__((ext_vector_type(4)));

#define MFMA32(a, b, c) __builtin_amdgcn_mfma_f32_16x16x32_f16((a), (b), (c), 0, 0, 0)
#define MFMA16(a, b, c) __builtin_amdgcn_mfma_f32_16x16x16f16((a), (b), (c), 0, 0, 0)

static constexpr int Bc = 2, Sc = 2048, DIMc = 1024, Hc = 16, HDc = 64;
static constexpr int Mc = Bc * Sc;        // 4096
static constexpr int NQKV = 3 * DIMc;     // 3072

__device__ __forceinline__ void gl_lds16(const _Float16* g, _Float16* l) {
  __builtin_amdgcn_global_load_lds(
      (const __attribute__((address_space(1))) void*)g,
      (__attribute__((address_space(3))) void*)l, 16, 0, 0);
}

// ---------------- prep kernels -------------------------------------------

__global__ void k_cvt_x(const float* __restrict__ x, _Float16* __restrict__ xh) {
  int i = blockIdx.x * 256 + threadIdx.x;
  xh[i] = (_Float16)x[i];
}

// W{q,k,v}[h][d][e] (fp32) -> WallT[p*1024 + h*64 + e][d] (f16)
__global__ __launch_bounds__(256) void k_prep_w(
    const float* __restrict__ Wq, const float* __restrict__ Wk,
    const float* __restrict__ Wv, _Float16* __restrict__ WallT) {
  __shared__ float Ls[64 * 65];
  const int dt = blockIdx.x, ph = blockIdx.y;
  const int p = ph >> 4, h = ph & 15;
  const float* W = (p == 0) ? Wq : (p == 1) ? Wk : Wv;
  const int tid = threadIdx.x;
  for (int c = tid; c < 4096; c += 256) {
    int dr = c >> 6, e = c & 63;
    Ls[e * 65 + dr] = W[h * 65536 + (dt * 64 + dr) * 64 + e];
  }
  __syncthreads();
  for (int c = tid; c < 4096; c += 256) {
    int e = c >> 6, dr = c & 63;
    WallT[(size_t)(p * 1024 + h * 64 + e) * 1024 + dt * 64 + dr] = (_Float16)Ls[e * 65 + dr];
  }
}

// Wo[d][n] (fp32) -> WoT[n][d] (f16)
__global__ __launch_bounds__(256) void k_prep_wo(
    const float* __restrict__ Wo, _Float16* __restrict__ WoT) {
  __shared__ float Ls[64 * 65];
  const int dt = blockIdx.x, nt = blockIdx.y;
  const int tid = threadIdx.x;
  for (int c = tid; c < 4096; c += 256) {
    int dr = c >> 6, nl = c & 63;
    Ls[nl * 65 + dr] = Wo[(dt * 64 + dr) * 1024 + nt * 64 + nl];
  }
  __syncthreads();
  for (int c = tid; c < 4096; c += 256) {
    int nl = c >> 6, dr = c & 63;
    WoT[(size_t)(nt * 64 + nl) * 1024 + dt * 64 + dr] = (_Float16)Ls[nl * 65 + dr];
  }
}

// ---------------- GEMM macro body (m97-style: global_load_lds staging) ----
// As/Bs stride 32 halves (contiguous, required by global_load_lds).

#define GEMM_PROLOG()                                                        \
  __shared__ _Float16 As[128 * 32];                                          \
  __shared__ _Float16 Bs[128 * 32];                                          \
  const int tid = threadIdx.x;                                               \
  const int lane = tid & 63, wave = tid >> 6;                                \
  const int quad = lane >> 4, mr = lane & 15;                                \
  const int wm = wave >> 1, wn = wave & 1;                                   \
  const int m0 = blockIdx.y * 128, n0 = blockIdx.x * 128;                    \
  f32x4 acc[4][4];                                                           \
  for (int i = 0; i < 4; i++)                                                \
    for (int j = 0; j < 4; j++) acc[i][j] = f32x4{0.f, 0.f, 0.f, 0.f};       \
  for (int k0 = 0; k0 < DIMc; k0 += 32) {                                    \
    __syncthreads();                                                         \
    for (int it = 0; it < 2; ++it) {                                         \
      int idx = it * 256 + tid;                                              \
      int row = idx >> 2, cb = idx & 3;                                      \
      _Float16* lb = (_Float16*)((it * 256 + wave * 64) * 8);                \
      gl_lds16(&A[(size_t)(m0 + row) * DIMc + k0 + cb * 8],                  \
               &As[(it * 256 + wave * 64) * 8]);                             \
      gl_lds16(&Bt[(size_t)(n0 + row) * DIMc + k0 + cb * 8],                 \
               &Bs[(it * 256 + wave * 64) * 8]);                             \
      (void)lb;                                                              \
    }                                                                        \
    __syncthreads();                                                         \
    half8 af[4], bf[4];                                                      \
    for (int i = 0; i < 4; i++)                                              \
      af[i] = *(const half8*)&As[(wm * 64 + i * 16 + mr) * 32 + quad * 8];   \
    for (int i = 0; i < 4; i++)                                              \
      bf[i] = *(const half8*)&Bs[(wn * 64 + i * 16 + mr) * 32 + quad * 8];   \
    for (int i = 0; i < 4; i++)                                              \
      for (int j = 0; j < 4; j++) acc[i][j] = MFMA32(af[i], bf[j], acc[i][j]); \
  }

// x @ [Wq|Wk] -> q,k [B,H,S,64] + bias.  grid (16, 32)
__global__ __launch_bounds__(256) void k_gemm_qk(
    const _Float16* __restrict__ A, const _Float16* __restrict__ Bt,
    const float* __restrict__ bq, const float* __restrict__ bk,
    _Float16* __restrict__ qh, _Float16* __restrict__ kh) {
  GEMM_PROLOG()
  for (int i = 0; i < 4; i++) {
    for (int j = 0; j < 4; j++) {
      int col = n0 + wn * 64 + j * 16 + mr;
      int p = col >> 10, rem = col & 1023;
      const float* bias = p ? bk : bq;
      _Float16* dst = p ? kh : qh;
      float bb = bias[rem];
      int h = rem >> 6, e = rem & 63;
      for (int r = 0; r < 4; r++) {
        int row = m0 + wm * 64 + i * 16 + quad * 4 + r;
        int b = row >> 11, s = row & 2047;
        dst[(((size_t)(b * Hc + h)) * Sc + s) * HDc + e] = (_Float16)(acc[i][j][r] + bb);
      }
    }
  }
}

// vT[b*1024+hd][s] = Wv'[hd][:] . x[s][:] + bv.  grid (32, 8)
__global__ __launch_bounds__(256) void k_gemm_vT(
    const _Float16* __restrict__ A, const _Float16* __restrict__ Bt,
    const float* __restrict__ bv, _Float16* __restrict__ vT) {
  GEMM_PROLOG()
  for (int i = 0; i < 4; i++) {
    int rowb = m0 + wm * 64 + i * 16 + quad * 4;
    for (int j = 0; j < 4; j++) {
      int col = n0 + wn * 64 + j * 16 + mr;
      int b = col >> 11, s = col & 2047;
      for (int r = 0; r < 4; r++) {
        int row = rowb + r;
        vT[(size_t)(b * 1024 + row) * Sc + s] = (_Float16)(acc[i][j][r] + bv[row]);
      }
    }
  }
}

// att @ Wo + bo -> out (fp32).  grid (8, 32)
__global__ __launch_bounds__(256) void k_gemm_out(
    const _Float16* __restrict__ A, const _Float16* __restrict__ Bt,
    const float* __restrict__ bo, float* __restrict__ out) {
  GEMM_PROLOG()
  for (int i = 0; i < 4; i++) {
    for (int j = 0; j < 4; j++) {
      int col = n0 + wn * 64 + j * 16 + mr;
      float bb = bo[col];
      for (int r = 0; r < 4; r++) {
        int row = m0 + wm * 64 + i * 16 + quad * 4 + r;
        out[(size_t)row * DIMc + col] = acc[i][j][r] + bb;
      }
    }
  }
}

// ---------------- flash attention (causal), S^T formulation ---------------
// 64 q-rows/block, 4 waves x 16 q-rows. 64-kv tiles, dbuf via global_load_lds.
// grid: x=32 (qt, long/short interleaved), y=32 (b*h). LDS 32 KB -> 4 blk/CU.

__global__ __launch_bounds__(256, 4) void k_attn(
    const _Float16* __restrict__ qg, const _Float16* __restrict__ kg,
    const _Float16* __restrict__ vTg, _Float16* __restrict__ att) {
  const int xb = blockIdx.x;
  const int qt = (xb & 1) ? (xb >> 1) : (31 - (xb >> 1));
  const int bh = blockIdx.y;
  const int b = bh >> 4, h = bh & 15;
  const int tid = threadIdx.x, wave = tid >> 6, lane = tid & 63;
  const int quad = lane >> 4, mr = lane & 15, m7 = mr & 7;
  const size_t base = (size_t)bh * (Sc * HDc);
  const size_t vbase = ((size_t)b * 1024 + h * 64) * Sc;

  // XOR-swizzled (8-half blocks: blk' = blk ^ (row&7)), no padding.
  __shared__ _Float16 Ks[2][64 * 64];   // [kv][e]
  __shared__ _Float16 Vt[2][64 * 64];   // [e][kv]

  const int qbase = qt * 64 + wave * 16;

  // Q rows as B-operand for K.Q^T; fold 1/sqrt(64) into Q.
  half8 aq[2];
  for (int c = 0; c < 2; ++c) {
    half8 v = *(const half8*)&qg[base + (size_t)(qbase + mr) * 64 + c * 32 + quad * 8];
    for (int j = 0; j < 8; ++j) v[j] = v[j] * (_Float16)0.125f;
    aq[c] = v;
  }

  f32x4 o[4];
  for (int i = 0; i < 4; i++) o[i] = f32x4{0.f, 0.f, 0.f, 0.f};
  float m_i = -3e30f, l_i = 0.f;

  const int nt = qt + 1;

  // stage tile 0 -> buf 0
  for (int it = 0; it < 2; ++it) {
    int idx = it * 256 + tid;
    int row = idx >> 3, scb = (idx & 7) ^ (row & 7);
    gl_lds16(kg + base + (size_t)row * 64 + scb * 8, &Ks[0][(it * 256 + wave * 64) * 8]);
    gl_lds16(vTg + vbase + (size_t)row * Sc + scb * 8, &Vt[0][(it * 256 + wave * 64) * 8]);
  }
  __syncthreads();

  for (int t = 0; t < nt; ++t) {
    const int cur = t & 1;
    if (t + 1 < nt) {
      const int nxt = cur ^ 1;
      const _Float16* ks = kg + base + (size_t)(t + 1) * 64 * 64;
      const _Float16* vs = vTg + vbase + (t + 1) * 64;
      for (int it = 0; it < 2; ++it) {
        int idx = it * 256 + tid;
        int row = idx >> 3, scb = (idx & 7) ^ (row & 7);
        gl_lds16(ks + (size_t)row * 64 + scb * 8, &Ks[nxt][(it * 256 + wave * 64) * 8]);
        gl_lds16(vs + (size_t)row * Sc + scb * 8, &Vt[nxt][(it * 256 + wave * 64) * 8]);
      }
    }

    // S^T[kv][q] = K . Q^T  (4 kv-frags of 16)
    f32x4 sf[4];
    for (int kf = 0; kf < 4; ++kf) {
      const int r0 = (kf * 16 + mr) * 64;
      half8 k0 = *(const half8*)&Ks[cur][r0 + ((quad ^ m7) * 8)];
      half8 k1 = *(const half8*)&Ks[cur][r0 + (((quad ^ 4) ^ m7) * 8)];
      f32x4 z = {0.f, 0.f, 0.f, 0.f};
      z = MFMA32(k0, aq[0], z);
      z = MFMA32(k1, aq[1], z);
      sf[kf] = z;
    }

    // causal mask (diagonal tiles only; lane holds kv=t*64+kf*16+quad*4+r, q=qbase+mr)
    if (t * 64 + 63 > qbase) {
      const int q = qbase + mr;
      for (int kf = 0; kf < 4; ++kf) {
        int kvb = t * 64 + kf * 16 + quad * 4;
        for (int r = 0; r < 4; ++r)
          if (kvb + r > q) sf[kf][r] = -3e30f;
      }
    }

    // online softmax: per-lane state for q=mr (cross-quad reduce: xor 16,32)
    float rm = -3e30f;
    for (int kf = 0; kf < 4; ++kf)
      for (int r = 0; r < 4; ++r) rm = fmaxf(rm, sf[kf][r]);
    rm = fmaxf(rm, __shfl_xor(rm, 16, 64));
    rm = fmaxf(rm, __shfl_xor(rm, 32, 64));

    float mn = fmaxf(m_i, rm);
    float alpha = __expf(m_i - mn);
    m_i = mn;

    float rs = 0.f;
    half4 pf[4];
    for (int kf = 0; kf < 4; ++kf) {
      half4 pp;
      for (int r = 0; r < 4; ++r) {
        float p = __expf(sf[kf][r] - mn);
        rs += p;
        pp[r] = (_Float16)p;
      }
      pf[kf] = pp;
    }
    rs += __shfl_xor(rs, 16, 64);
    rs += __shfl_xor(rs, 32, 64);
    l_i = l_i * alpha + rs;

    for (int nf = 0; nf < 4; ++nf)
      for (int r = 0; r < 4; ++r) o[nf][r] *= alpha;

    // O^T[e][q] += V^T . P^T   (P^T direct from regs: C/D layout == K16 B-frag)
    for (int nf = 0; nf < 4; ++nf) {
      const int er = (nf * 16 + mr) * 64;
      for (int kc = 0; kc < 4; ++kc) {
        int kb = kc * 2 + (quad >> 1);
        half4 vv = *(const half4*)&Vt[cur][er + ((kb ^ m7) * 8) + (quad & 1) * 4];
        o[nf] = MFMA16(vv, pf[kc], o[nf]);
      }
    }
    __syncthreads();
  }

  // O^T lane holds e=nf*16+quad*4+r, q=qbase+mr  -> att[b][s][h*64+e]
  const float inv = 1.0f / l_i;
  for (int nf = 0; nf < 4; ++nf) {
    half4 ov;
    for (int r = 0; r < 4; ++r) ov[r] = (_Float16)(o[nf][r] * inv);
    *(half4*)&att[((size_t)(b * Sc + qbase + mr)) * DIMc + h * 64 + nf * 16 + quad * 4] = ov;
  }
}

// ---------------- launch ---------------------------------------------------

extern "C" void kernel_launch(void* const* d_in, const int* in_sizes, int n_in,
                              void* d_out, int out_size, void* d_ws, size_t ws_size,
                              hipStream_t stream) {
  const float* x  = (const float*)d_in[0];
  const float* Wq = (const float*)d_in[1];
  const float* bq = (const float*)d_in[2];
  const float* Wk = (const float*)d_in[3];
  const float* bk = (const float*)d_in[4];
  const float* Wv = (const float*)d_in[5];
  const float* bv = (const float*)d_in[6];
  const float* Wo = (const float*)d_in[7];
  const float* bo = (const float*)d_in[8];
  float* out = (float*)d_out;

  _Float16* p = (_Float16*)d_ws;
  _Float16* xh    = p; p += (size_t)Mc * DIMc;               // 4M halves
  _Float16* WallT = p; p += (size_t)NQKV * DIMc;             // 3M
  _Float16* WoT   = p; p += (size_t)DIMc * DIMc;             // 1M
  _Float16* qh    = p; p += (size_t)Bc * Hc * Sc * HDc;      // 4M
  _Float16* kh    = p; p += (size_t)Bc * Hc * Sc * HDc;      // 4M
  _Float16* vT    = p; p += (size_t)Bc * Hc * Sc * HDc;      // 4M
  _Float16* atth  = p;                                       // 4M => 48 MB total

  k_cvt_x<<<(Mc * DIMc) / 256, 256, 0, stream>>>(x, xh);
  k_prep_w<<<dim3(16, 48), 256, 0, stream>>>(Wq, Wk, Wv, WallT);
  k_prep_wo<<<dim3(16, 16), 256, 0, stream>>>(Wo, WoT);

  k_gemm_qk<<<dim3(16, Mc / 128), 256, 0, stream>>>(xh, WallT, bq, bk, qh, kh);
  k_gemm_vT<<<dim3(Mc / 128, 8), 256, 0, stream>>>(
      WallT + (size_t)2048 * DIMc, xh, bv, vT);

  k_attn<<<dim3(32, Bc * Hc), 256, 0, stream>>>(qh, kh, vT, atth);

  k_gemm_out<<<dim3(DIMc / 128, Mc / 128), 256, 0, stream>>>(atth, WoT, bo, out);
}